// Round 1
// baseline (709.127 us; speedup 1.0000x reference)
//
#include <hip/hip_runtime.h>
#include <hip/hip_bf16.h>

// LSTM (T=512, B=512, IN=300, H=16) + MLP head, fp32 in/out.
// Phase 1: xg[b][t][g] = x[t*B+b][:] . W_ih[g][:] + (b_ih+b_hh)[g]
//          via bf16 MFMA 16x16x32, direct-from-global fragments (no LDS).
// Phase 2: scan with lane = (batch q, hidden j): 4 batches/wave, in-lane
//          gate math, h distributed by 16 parallel ds_bpermute.

#define T_STEPS 512
#define BATCH   512
#define K_IN    300
#define NG      64   // 4*HIDDEN
#define HID     16
#define DPF     4    // scan prefetch ring depth (per gate stream)

typedef float  f32x4  __attribute__((ext_vector_type(4)));
typedef float  f32x8  __attribute__((ext_vector_type(8)));
typedef __bf16 bf16x8 __attribute__((ext_vector_type(8)));

static __device__ __forceinline__ bf16x8 cvt8(float4 lo, float4 hi) {
    f32x8 t;
    t[0] = lo.x; t[1] = lo.y; t[2] = lo.z; t[3] = lo.w;
    t[4] = hi.x; t[5] = hi.y; t[6] = hi.z; t[7] = hi.w;
    return __builtin_convertvector(t, bf16x8);
}

// ---------------------------------------------------------------------------
// MFMA GEMM: block = 4 waves x 16 rows = 64 rows. Wave computes its 16-row
// strip x all 64 gates (4 n-tiles, f32x4 acc each). A-frag: lane(m=lane&15,
// quad=lane>>4) reads x[row][k0+quad*8 .. +8] = 2 float4 -> cvt bf16.
// B-frag mirrors it on W rows (n=lane&15). K = 9 full 32-tiles + masked tail.
// ---------------------------------------------------------------------------
__global__ __launch_bounds__(256) void xg_gemm(
    const float* __restrict__ x,      // [T*B][300]
    const float* __restrict__ W,      // [64][300]
    const float* __restrict__ b_ih,   // [64]
    const float* __restrict__ b_hh,   // [64]
    float* __restrict__ xg)           // [B][T][64]
{
    const int lane = threadIdx.x & 63;
    const int wv   = threadIdx.x >> 6;
    const int m16  = lane & 15;
    const int quad = lane >> 4;
    const int row0 = blockIdx.x * 64 + wv * 16;

    const float* xr = x + (size_t)(row0 + m16) * K_IN;
    const float* wr = W + (size_t)m16 * K_IN;

    f32x4 acc[4];
#pragma unroll
    for (int nt = 0; nt < 4; ++nt) acc[nt] = (f32x4){0.f, 0.f, 0.f, 0.f};

#pragma unroll 1
    for (int ks = 0; ks < 9; ++ks) {
        const int k = ks * 32 + quad * 8;
        const bf16x8 af = cvt8(*(const float4*)(xr + k),
                               *(const float4*)(xr + k + 4));
#pragma unroll
        for (int nt = 0; nt < 4; ++nt) {
            const float* wp = wr + (size_t)nt * 16 * K_IN + k;
            const bf16x8 bf = cvt8(*(const float4*)(wp),
                                   *(const float4*)(wp + 4));
            acc[nt] = __builtin_amdgcn_mfma_f32_16x16x32_bf16(af, bf, acc[nt], 0, 0, 0);
        }
    }
    {   // tail tile k0=288: cols 300..319 must be zero (mask per quad)
        const int kb = 288 + quad * 8;
        const float4 z4 = {0.f, 0.f, 0.f, 0.f};
        const float4 alo = (kb + 3 < K_IN) ? *(const float4*)(xr + kb)     : z4;
        const float4 ahi = (kb + 7 < K_IN) ? *(const float4*)(xr + kb + 4) : z4;
        const bf16x8 af = cvt8(alo, ahi);
#pragma unroll
        for (int nt = 0; nt < 4; ++nt) {
            const float* wp = wr + (size_t)nt * 16 * K_IN + kb;
            const float4 blo = (kb + 3 < K_IN) ? *(const float4*)(wp)     : z4;
            const float4 bhi = (kb + 7 < K_IN) ? *(const float4*)(wp + 4) : z4;
            const bf16x8 bf = cvt8(blo, bhi);
            acc[nt] = __builtin_amdgcn_mfma_f32_16x16x32_bf16(af, bf, acc[nt], 0, 0, 0);
        }
    }

    // epilogue: C/D layout col=lane&15, row=quad*4+reg. Block rows share t.
    float bias[4];
#pragma unroll
    for (int nt = 0; nt < 4; ++nt)
        bias[nt] = b_ih[nt * 16 + m16] + b_hh[nt * 16 + m16];

#pragma unroll
    for (int reg = 0; reg < 4; ++reg) {
        const int R = row0 + quad * 4 + reg;   // = t*512 + b
        const int t = R >> 9;
        const int b = R & (BATCH - 1);
        float* op = xg + ((size_t)b * T_STEPS + t) * NG + m16;
        op[0]  = acc[0][reg] + bias[0];
        op[16] = acc[1][reg] + bias[1];
        op[32] = acc[2][reg] + bias[2];
        op[48] = acc[3][reg] + bias[3];
    }
}

// ---------------------------------------------------------------------------
// Scan: lane = (q=lane>>4, j=lane&15): batch blockIdx*4+q, hidden unit j.
// Per lane: all 4 W_hh gate rows (64 VGPR), i/f/g/o dots + c/h in-lane.
// h distributed via 16 parallel ds_bpermute from the lane's 16-group.
// xg [B][T][64]: 4 coalesced dword loads/step/lane, DPF=4 clamped ring.
// ---------------------------------------------------------------------------
__global__ __launch_bounds__(64) void lstm_scan(
    const float* __restrict__ xg,    // [B][T][64], biases included
    const float* __restrict__ Whh,   // [64][16]
    const float* __restrict__ W1,    // [64][16]
    const float* __restrict__ b1,    // [64]
    const float* __restrict__ W2,    // [64]
    const float* __restrict__ b2,    // [1]
    float* __restrict__ out)         // [B]
{
    const int lane = threadIdx.x;
    const int q = lane >> 4;         // batch sub-index 0..3
    const int j = lane & 15;         // hidden unit
    const int batch = blockIdx.x * 4 + q;
    const int pbase = (lane & 48) << 2;   // ds_bpermute group base (bytes)

    // W_hh rows j (i), j+16 (f), j+32 (g), j+48 (o)
    float wi[HID], wf[HID], wg[HID], wo[HID];
#pragma unroll
    for (int k = 0; k < HID; k += 4) {
        *(float4*)&wi[k] = *(const float4*)(Whh + (j     ) * HID + k);
        *(float4*)&wf[k] = *(const float4*)(Whh + (j + 16) * HID + k);
        *(float4*)&wg[k] = *(const float4*)(Whh + (j + 32) * HID + k);
        *(float4*)&wo[k] = *(const float4*)(Whh + (j + 48) * HID + k);
    }

    float c = 0.f;
    float hb[HID];
#pragma unroll
    for (int k = 0; k < HID; ++k) hb[k] = 0.f;

    const float* xgb = xg + (size_t)batch * T_STEPS * NG + j;  // t-stride 64

    float bi[DPF], bfr[DPF], bg[DPF], bo[DPF];
#pragma unroll
    for (int u = 0; u < DPF; ++u) {
        const float* pl = xgb + (size_t)u * NG;
        bi[u] = pl[0]; bfr[u] = pl[16]; bg[u] = pl[32]; bo[u] = pl[48];
    }

#pragma unroll 1
    for (int tt = 0; tt < T_STEPS; tt += DPF) {
#pragma unroll
        for (int u = 0; u < DPF; ++u) {
            const int t = tt + u;
            const float ci = bi[u], cf = bfr[u], cg = bg[u], co = bo[u];
            int tl = t + DPF; if (tl > T_STEPS - 1) tl = T_STEPS - 1;
            const float* pl = xgb + (size_t)tl * NG;
            bi[u] = pl[0]; bfr[u] = pl[16]; bg[u] = pl[32]; bo[u] = pl[48];

            // four in-lane dots over the group's h (hb)
            float si = ci, sf = cf, sg = cg, so = co;
#pragma unroll
            for (int k = 0; k < HID; ++k) {
                si = fmaf(wi[k], hb[k], si);
                sf = fmaf(wf[k], hb[k], sf);
                sg = fmaf(wg[k], hb[k], sg);
                so = fmaf(wo[k], hb[k], so);
            }

            const float ai = __builtin_amdgcn_rcpf(1.f + __expf(-si));
            const float af = __builtin_amdgcn_rcpf(1.f + __expf(-sf));
            const float ao = __builtin_amdgcn_rcpf(1.f + __expf(-so));
            const float tg = fmaf(2.f, __builtin_amdgcn_rcpf(1.f + __expf(-2.f * sg)), -1.f);

            c = fmaf(af, c, ai * tg);
            const float th = fmaf(2.f, __builtin_amdgcn_rcpf(1.f + __expf(-2.f * c)), -1.f);
            const float h = ao * th;

            // distribute h across the 16-lane group (parallel bpermutes)
            const int hI = __float_as_int(h);
#pragma unroll
            for (int k = 0; k < HID; ++k)
                hb[k] = __int_as_float(__builtin_amdgcn_ds_bpermute(pbase + 4 * k, hI));
        }
    }

    // ---- fused MLP head: lane handles z rows {j, j+16, j+32, j+48}
    float y = 0.f;
#pragma unroll
    for (int u4 = 0; u4 < 4; ++u4) {
        const int u = u4 * 16 + j;
        float z = b1[u];
#pragma unroll
        for (int k = 0; k < HID; ++k)
            z = fmaf(W1[u * HID + k], hb[k], z);
        z = fmaxf(z, 0.f);
        y = fmaf(z, W2[u], y);
    }
    // reduce within the 16-lane group
#pragma unroll
    for (int m = 8; m; m >>= 1) y += __shfl_xor(y, m, 64);

    if (j == 0)
        out[batch] = 4.f * __builtin_amdgcn_rcpf(1.f + __expf(-(y + b2[0])));
}

extern "C" void kernel_launch(void* const* d_in, const int* in_sizes, int n_in,
                              void* d_out, int out_size, void* d_ws, size_t ws_size,
                              hipStream_t stream) {
    const float* x    = (const float*)d_in[0];
    const float* W_ih = (const float*)d_in[1];
    const float* W_hh = (const float*)d_in[2];
    const float* b_ih = (const float*)d_in[3];
    const float* b_hh = (const float*)d_in[4];
    const float* W1   = (const float*)d_in[5];
    const float* b1   = (const float*)d_in[6];
    const float* W2   = (const float*)d_in[7];
    const float* b2   = (const float*)d_in[8];
    float* out = (float*)d_out;
    float* xg  = (float*)d_ws;   // [B][T][64] = 64 MiB

    xg_gemm<<<dim3(T_STEPS * BATCH / 64), dim3(256), 0, stream>>>(x, W_ih, b_ih, b_hh, xg);
    lstm_scan<<<dim3(BATCH / 4), dim3(64), 0, stream>>>(xg, W_hh, W1, b1, W2, b2, out);
}

// Round 2
// 566.527 us; speedup vs baseline: 1.2517x; 1.2517x over previous
//
#include <hip/hip_runtime.h>
#include <hip/hip_bf16.h>

// LSTM (T=512, B=512, IN=300, H=16) + MLP head, fp32 in/out.
// Phase 1: xg[b][t][j][4] = x . W_ih^T + (b_ih+b_hh), bf16 MFMA 16x16x32.
//          Per wave: ALL 10 A k-tiles prefetched to VGPRs up front (deep MLP),
//          W staged once per block into fragment-packed bf16 LDS (tail zeros
//          baked in) -> K-loop is pure LDS+MFMA, no global waits.
// Phase 2: scan, lane = (batch q, hidden j). One coalesced float4/step
//          (gates packed), DPF=8 register ring, float2-packed dots.

#define T_STEPS 512
#define BATCH   512
#define K_IN    300
#define NG      64   // 4*HIDDEN
#define HID     16
#define DPF     8    // scan prefetch ring depth (steps ahead)

typedef float  f32x2  __attribute__((ext_vector_type(2)));
typedef float  f32x4  __attribute__((ext_vector_type(4)));
typedef float  f32x8  __attribute__((ext_vector_type(8)));
typedef __bf16 bf16x8 __attribute__((ext_vector_type(8)));

static __device__ __forceinline__ bf16x8 cvt8(float4 lo, float4 hi) {
    f32x8 t;
    t[0] = lo.x; t[1] = lo.y; t[2] = lo.z; t[3] = lo.w;
    t[4] = hi.x; t[5] = hi.y; t[6] = hi.z; t[7] = hi.w;
    return __builtin_convertvector(t, bf16x8);
}

// ---------------------------------------------------------------------------
// MFMA GEMM: block = 4 waves x 16 rows = 64 consecutive rows of x.
// Wave computes its 16-row strip x all 64 gates (4 n-tiles, f32x4 acc each).
// A-frag: lane(m=lane&15, quad=lane>>4) holds x[row][k0+quad*8..+8).
// All 10 A k-tiles loaded to VGPRs before the K-loop (tail masked).
// W: each wave cvt-stages its gate-type tile (nt=wv) for all 10 k-tiles into
// LDS, fragment-packed: slot (ks,nt), entry lane*16B = that lane's B-frag.
// ---------------------------------------------------------------------------
__global__ __launch_bounds__(256) void xg_gemm(
    const float* __restrict__ x,      // [T*B][300]
    const float* __restrict__ W,      // [64][300]
    const float* __restrict__ b_ih,   // [64]
    const float* __restrict__ b_hh,   // [64]
    float* __restrict__ xg)           // [B][T][16][4]
{
    __shared__ __align__(16) __bf16 Wl[40 * 512];   // 40 KiB, frag-packed

    const int lane = threadIdx.x & 63;
    const int wv   = threadIdx.x >> 6;
    const int m16  = lane & 15;
    const int quad = lane >> 4;
    const int row0 = blockIdx.x * 64 + wv * 16;
    const float4 z4 = {0.f, 0.f, 0.f, 0.f};

    const float* xr = x + (size_t)(row0 + m16) * K_IN;

    // ---- A prefetch: 10 k-tiles x 2 float4, all in flight (tail guarded)
    float4 alo[10], ahi[10];
#pragma unroll
    for (int ks = 0; ks < 10; ++ks) {
        const int k = ks * 32 + quad * 8;
        alo[ks] = (k + 3 < K_IN) ? *(const float4*)(xr + k)     : z4;
        ahi[ks] = (k + 7 < K_IN) ? *(const float4*)(xr + k + 4) : z4;
    }

    // ---- W stage: wave wv handles gate-type tile nt=wv for all k-tiles
    {
        const float* wrow = W + (size_t)(wv * 16 + m16) * K_IN;
#pragma unroll
        for (int ks = 0; ks < 10; ++ks) {
            const int k = ks * 32 + quad * 8;
            const float4 lo = (k + 3 < K_IN) ? *(const float4*)(wrow + k)     : z4;
            const float4 hi = (k + 7 < K_IN) ? *(const float4*)(wrow + k + 4) : z4;
            *(bf16x8*)&Wl[(ks * 4 + wv) * 512 + lane * 8] = cvt8(lo, hi);
        }
    }
    __syncthreads();

    f32x4 acc[4];
#pragma unroll
    for (int nt = 0; nt < 4; ++nt) acc[nt] = (f32x4){0.f, 0.f, 0.f, 0.f};

#pragma unroll
    for (int ks = 0; ks < 10; ++ks) {
        const bf16x8 af = cvt8(alo[ks], ahi[ks]);
#pragma unroll
        for (int nt = 0; nt < 4; ++nt) {
            const bf16x8 bf = *(const bf16x8*)&Wl[(ks * 4 + nt) * 512 + lane * 8];
            acc[nt] = __builtin_amdgcn_mfma_f32_16x16x32_bf16(af, bf, acc[nt], 0, 0, 0);
        }
    }

    // ---- epilogue: C/D layout col(m16)=gate-row n, row=quad*4+reg.
    // Packed output: xg[b][t][j=m16][gate-type 0..3] -> one dwordx4 per reg.
    float bias[4];
#pragma unroll
    for (int nt = 0; nt < 4; ++nt)
        bias[nt] = b_ih[nt * 16 + m16] + b_hh[nt * 16 + m16];

#pragma unroll
    for (int reg = 0; reg < 4; ++reg) {
        const int R = row0 + quad * 4 + reg;   // = t*512 + b
        const int t = R >> 9;
        const int b = R & (BATCH - 1);
        float4 o;
        o.x = acc[0][reg] + bias[0];
        o.y = acc[1][reg] + bias[1];
        o.z = acc[2][reg] + bias[2];
        o.w = acc[3][reg] + bias[3];
        *(float4*)(xg + ((size_t)b * T_STEPS + t) * NG + m16 * 4) = o;
    }
}

// ---------------------------------------------------------------------------
// Scan: lane = (q=lane>>4, j=lane&15): batch blockIdx*4+q, hidden unit j.
// xg [b][t][j][4]: ONE coalesced float4 per step per lane (i,f,g,o).
// DPF=8 register ring; dots as float2 packed fma; h distributed via 16
// parallel ds_bpermute within the 16-lane group.
// ---------------------------------------------------------------------------
__global__ __launch_bounds__(64) void lstm_scan(
    const float* __restrict__ xg,    // [B][T][16][4], biases included
    const float* __restrict__ Whh,   // [64][16]
    const float* __restrict__ W1,    // [64][16]
    const float* __restrict__ b1,    // [64]
    const float* __restrict__ W2,    // [64]
    const float* __restrict__ b2,    // [1]
    float* __restrict__ out)         // [B]
{
    const int lane = threadIdx.x;
    const int q = lane >> 4;         // batch sub-index 0..3
    const int j = lane & 15;         // hidden unit
    const int batch = blockIdx.x * 4 + q;
    const int pbase = (lane & 48) << 2;   // ds_bpermute group base (bytes)

    // W_hh rows j (i), j+16 (f), j+32 (g), j+48 (o) as float2 pairs
    f32x2 wi2[8], wf2[8], wg2[8], wo2[8];
#pragma unroll
    for (int k4 = 0; k4 < 4; ++k4) {
        float4 a;
        a = *(const float4*)(Whh + (j     ) * HID + k4 * 4);
        wi2[k4 * 2] = (f32x2){a.x, a.y}; wi2[k4 * 2 + 1] = (f32x2){a.z, a.w};
        a = *(const float4*)(Whh + (j + 16) * HID + k4 * 4);
        wf2[k4 * 2] = (f32x2){a.x, a.y}; wf2[k4 * 2 + 1] = (f32x2){a.z, a.w};
        a = *(const float4*)(Whh + (j + 32) * HID + k4 * 4);
        wg2[k4 * 2] = (f32x2){a.x, a.y}; wg2[k4 * 2 + 1] = (f32x2){a.z, a.w};
        a = *(const float4*)(Whh + (j + 48) * HID + k4 * 4);
        wo2[k4 * 2] = (f32x2){a.x, a.y}; wo2[k4 * 2 + 1] = (f32x2){a.z, a.w};
    }

    float c = 0.f;
    f32x2 hb2[8];
#pragma unroll
    for (int k = 0; k < 8; ++k) hb2[k] = (f32x2){0.f, 0.f};

    const float* xgb = xg + (size_t)batch * T_STEPS * NG + j * 4;  // t-stride 64

    float4 ring[DPF];
#pragma unroll
    for (int u = 0; u < DPF; ++u)
        ring[u] = *(const float4*)(xgb + (size_t)u * NG);

#pragma unroll 1
    for (int tt = 0; tt < T_STEPS; tt += DPF) {
#pragma unroll
        for (int u = 0; u < DPF; ++u) {
            const int t = tt + u;
            const float4 v = ring[u];
            int tl = t + DPF; if (tl > T_STEPS - 1) tl = T_STEPS - 1;
            ring[u] = *(const float4*)(xgb + (size_t)tl * NG);

            // four packed dots over the group's h
            f32x2 si2 = (f32x2){v.x, 0.f};
            f32x2 sf2 = (f32x2){v.y, 0.f};
            f32x2 sg2 = (f32x2){v.z, 0.f};
            f32x2 so2 = (f32x2){v.w, 0.f};
#pragma unroll
            for (int k = 0; k < 8; ++k) {
                si2 += wi2[k] * hb2[k];
                sf2 += wf2[k] * hb2[k];
                sg2 += wg2[k] * hb2[k];
                so2 += wo2[k] * hb2[k];
            }
            const float si = si2[0] + si2[1];
            const float sf = sf2[0] + sf2[1];
            const float sg = sg2[0] + sg2[1];
            const float so = so2[0] + so2[1];

            const float ai = __builtin_amdgcn_rcpf(1.f + __expf(-si));
            const float af = __builtin_amdgcn_rcpf(1.f + __expf(-sf));
            const float ao = __builtin_amdgcn_rcpf(1.f + __expf(-so));
            const float tg = fmaf(2.f, __builtin_amdgcn_rcpf(1.f + __expf(-2.f * sg)), -1.f);

            c = fmaf(af, c, ai * tg);
            const float th = fmaf(2.f, __builtin_amdgcn_rcpf(1.f + __expf(-2.f * c)), -1.f);
            const float h = ao * th;

            // distribute h across the 16-lane group (parallel bpermutes)
            const int hI = __float_as_int(h);
#pragma unroll
            for (int k = 0; k < HID; ++k)
                hb2[k >> 1][k & 1] =
                    __int_as_float(__builtin_amdgcn_ds_bpermute(pbase + 4 * k, hI));
        }
    }

    // ---- fused MLP head: lane handles z rows {j, j+16, j+32, j+48}
    float y = 0.f;
#pragma unroll
    for (int u4 = 0; u4 < 4; ++u4) {
        const int u = u4 * 16 + j;
        float z = b1[u];
#pragma unroll
        for (int k = 0; k < HID; ++k)
            z = fmaf(W1[u * HID + k], hb2[k >> 1][k & 1], z);
        z = fmaxf(z, 0.f);
        y = fmaf(z, W2[u], y);
    }
    // reduce within the 16-lane group
#pragma unroll
    for (int m = 8; m; m >>= 1) y += __shfl_xor(y, m, 64);

    if (j == 0)
        out[batch] = 4.f * __builtin_amdgcn_rcpf(1.f + __expf(-(y + b2[0])));
}

extern "C" void kernel_launch(void* const* d_in, const int* in_sizes, int n_in,
                              void* d_out, int out_size, void* d_ws, size_t ws_size,
                              hipStream_t stream) {
    const float* x    = (const float*)d_in[0];
    const float* W_ih = (const float*)d_in[1];
    const float* W_hh = (const float*)d_in[2];
    const float* b_ih = (const float*)d_in[3];
    const float* b_hh = (const float*)d_in[4];
    const float* W1   = (const float*)d_in[5];
    const float* b1   = (const float*)d_in[6];
    const float* W2   = (const float*)d_in[7];
    const float* b2   = (const float*)d_in[8];
    float* out = (float*)d_out;
    float* xg  = (float*)d_ws;   // [B][T][64] = 64 MiB

    xg_gemm<<<dim3(T_STEPS * BATCH / 64), dim3(256), 0, stream>>>(x, W_ih, b_ih, b_hh, xg);
    lstm_scan<<<dim3(BATCH / 4), dim3(64), 0, stream>>>(xg, W_hh, W1, b1, W2, b2, out);
}

// Round 3
// 529.157 us; speedup vs baseline: 1.3401x; 1.0706x over previous
//
#include <hip/hip_runtime.h>
#include <hip/hip_bf16.h>

// LSTM (T=512, B=512, IN=300, H=16) + MLP head, fp32 in/out.
// Phase 1: xg[b][t][j][4] = x . W_ih^T + (b_ih+b_hh), bf16 MFMA 16x16x32.
//          Per wave: ALL 10 A k-tiles prefetched to VGPRs up front,
//          W staged once per block into fragment-packed bf16 LDS.
// Phase 2: scan, ONE batch per wave, ONE gate-row per lane (lane = qd*16+j).
//          h[16] is wave-uniform -> kept via v_readlane (no LDS on h path).
//          xg staged through LDS in 16-step chunks, async reg->LDS split.

#define T_STEPS 512
#define BATCH   512
#define K_IN    300
#define NG      64   // 4*HIDDEN
#define HID     16
#define CHUNK   16   // scan: t-steps per LDS stage

typedef float  f32x4  __attribute__((ext_vector_type(4)));
typedef float  f32x8  __attribute__((ext_vector_type(8)));
typedef __bf16 bf16x8 __attribute__((ext_vector_type(8)));

static __device__ __forceinline__ bf16x8 cvt8(float4 lo, float4 hi) {
    f32x8 t;
    t[0] = lo.x; t[1] = lo.y; t[2] = lo.z; t[3] = lo.w;
    t[4] = hi.x; t[5] = hi.y; t[6] = hi.z; t[7] = hi.w;
    return __builtin_convertvector(t, bf16x8);
}

// ---------------------------------------------------------------------------
// MFMA GEMM (unchanged from round 2): block = 4 waves x 16 rows.
// ---------------------------------------------------------------------------
__global__ __launch_bounds__(256) void xg_gemm(
    const float* __restrict__ x,      // [T*B][300]
    const float* __restrict__ W,      // [64][300]
    const float* __restrict__ b_ih,   // [64]
    const float* __restrict__ b_hh,   // [64]
    float* __restrict__ xg)           // [B][T][16][4]
{
    __shared__ __align__(16) __bf16 Wl[40 * 512];   // 40 KiB, frag-packed

    const int lane = threadIdx.x & 63;
    const int wv   = threadIdx.x >> 6;
    const int m16  = lane & 15;
    const int quad = lane >> 4;
    const int row0 = blockIdx.x * 64 + wv * 16;
    const float4 z4 = {0.f, 0.f, 0.f, 0.f};

    const float* xr = x + (size_t)(row0 + m16) * K_IN;

    // ---- A prefetch: 10 k-tiles x 2 float4, all in flight (tail guarded)
    float4 alo[10], ahi[10];
#pragma unroll
    for (int ks = 0; ks < 10; ++ks) {
        const int k = ks * 32 + quad * 8;
        alo[ks] = (k + 3 < K_IN) ? *(const float4*)(xr + k)     : z4;
        ahi[ks] = (k + 7 < K_IN) ? *(const float4*)(xr + k + 4) : z4;
    }

    // ---- W stage: wave wv handles gate-type tile nt=wv for all k-tiles
    {
        const float* wrow = W + (size_t)(wv * 16 + m16) * K_IN;
#pragma unroll
        for (int ks = 0; ks < 10; ++ks) {
            const int k = ks * 32 + quad * 8;
            const float4 lo = (k + 3 < K_IN) ? *(const float4*)(wrow + k)     : z4;
            const float4 hi = (k + 7 < K_IN) ? *(const float4*)(wrow + k + 4) : z4;
            *(bf16x8*)&Wl[(ks * 4 + wv) * 512 + lane * 8] = cvt8(lo, hi);
        }
    }
    __syncthreads();

    f32x4 acc[4];
#pragma unroll
    for (int nt = 0; nt < 4; ++nt) acc[nt] = (f32x4){0.f, 0.f, 0.f, 0.f};

#pragma unroll
    for (int ks = 0; ks < 10; ++ks) {
        const bf16x8 af = cvt8(alo[ks], ahi[ks]);
#pragma unroll
        for (int nt = 0; nt < 4; ++nt) {
            const bf16x8 bf = *(const bf16x8*)&Wl[(ks * 4 + nt) * 512 + lane * 8];
            acc[nt] = __builtin_amdgcn_mfma_f32_16x16x32_bf16(af, bf, acc[nt], 0, 0, 0);
        }
    }

    // ---- epilogue: packed output xg[b][t][j=m16][gate 0..3], one dwordx4
    float bias[4];
#pragma unroll
    for (int nt = 0; nt < 4; ++nt)
        bias[nt] = b_ih[nt * 16 + m16] + b_hh[nt * 16 + m16];

#pragma unroll
    for (int reg = 0; reg < 4; ++reg) {
        const int R = row0 + quad * 4 + reg;   // = t*512 + b
        const int t = R >> 9;
        const int b = R & (BATCH - 1);
        float4 o;
        o.x = acc[0][reg] + bias[0];
        o.y = acc[1][reg] + bias[1];
        o.z = acc[2][reg] + bias[2];
        o.w = acc[3][reg] + bias[3];
        *(float4*)(xg + ((size_t)b * T_STEPS + t) * NG + m16 * 4) = o;
    }
}

// ---------------------------------------------------------------------------
// Scan v3: one batch per wave (512 blocks x 64 threads), lane = gate-row
// (qd = lane>>4 in {i,f,g,o}, j = lane&15 = hidden unit).
//   per step: 16-FMA dot (h in wave-uniform regs) -> 1 activation chain
//   (uniform via per-gate constants) -> 4 ds_bpermute act gather -> c,h
//   (computed redundantly in all quads, consistent) -> 16 v_readlane.
// xg rows staged via LDS double-buffered 16-step chunks; next chunk's
// global loads issue BEFORE the compute, ds_write after (T14 split).
// ---------------------------------------------------------------------------
__global__ __launch_bounds__(64) void lstm_scan(
    const float* __restrict__ xg,    // [B][T][16][4], biases included
    const float* __restrict__ Whh,   // [64][16]
    const float* __restrict__ W1,    // [64][16]
    const float* __restrict__ b1,    // [64]
    const float* __restrict__ W2,    // [64]
    const float* __restrict__ b2,    // [1]
    float* __restrict__ out)         // [B]
{
    __shared__ __align__(16) float xs[2][CHUNK][NG];   // 8 KiB

    const int lane  = threadIdx.x;       // 0..63 = gate-row
    const int j     = lane & 15;         // hidden unit
    const int qd    = lane >> 4;         // 0:i 1:f 2:g 3:o
    const int batch = blockIdx.x;
    const int perm  = j * 4 + qd;        // element of packed 64-row

    // W_hh row 'lane' (= qd*16 + j)
    float w[HID];
#pragma unroll
    for (int k = 0; k < HID; k += 4)
        *(float4*)&w[k] = *(const float4*)(Whh + lane * HID + k);

    // activation constants: sigmoid for i/f/o, tanh for g (= 2*sig(2x)-1)
    const float kk = (qd == 2) ? -2.f : -1.f;
    const float mm = (qd == 2) ?  2.f :  1.f;
    const float nn = (qd == 2) ? -1.f :  0.f;

    // bpermute byte-addresses: act of unit j from each gate quad
    const int aI = 4 * j, aF = 4 * (16 + j), aG = 4 * (32 + j), aO = 4 * (48 + j);

    const float* xb = xg + (size_t)batch * T_STEPS * NG;

    // prologue: stage chunk 0
#pragma unroll
    for (int q = 0; q < 4; ++q)
        *(float4*)((float*)xs + q * 256 + lane * 4) =
            *(const float4*)(xb + q * 256 + lane * 4);

    float c = 0.f;
    float hs[HID];
#pragma unroll
    for (int k = 0; k < HID; ++k) hs[k] = 0.f;

#pragma unroll 1
    for (int ci = 0; ci < T_STEPS / CHUNK; ++ci) {
        const int cur = ci & 1;

        // issue next chunk's global loads early (latency hides under compute)
        float4 nx0, nx1, nx2, nx3;
        if (ci < T_STEPS / CHUNK - 1) {
            const float* src = xb + (size_t)(ci + 1) * CHUNK * NG;
            nx0 = *(const float4*)(src +   0 + lane * 4);
            nx1 = *(const float4*)(src + 256 + lane * 4);
            nx2 = *(const float4*)(src + 512 + lane * 4);
            nx3 = *(const float4*)(src + 768 + lane * 4);
        }

        const float* bp = (const float*)xs + cur * (CHUNK * NG) + perm;

#pragma unroll
        for (int tin = 0; tin < CHUNK; ++tin) {
            const float pre = bp[tin * NG];

            // 16-FMA dot, 4 partials for ILP; hs is wave-uniform
            float p0 = pre, p1 = 0.f, p2 = 0.f, p3 = 0.f;
#pragma unroll
            for (int k = 0; k < 4; ++k) {
                p0 = fmaf(w[k],      hs[k],      p0);
                p1 = fmaf(w[k + 4],  hs[k + 4],  p1);
                p2 = fmaf(w[k + 8],  hs[k + 8],  p2);
                p3 = fmaf(w[k + 12], hs[k + 12], p3);
            }
            const float s = (p0 + p1) + (p2 + p3);

            // uniform activation: a = 1/(1+exp(kk*s)); act = a*mm + nn
            const float a   = __builtin_amdgcn_rcpf(1.f + __expf(kk * s));
            const float act = fmaf(a, mm, nn);

            // gather the 4 gate activations of unit j
            const int av = __float_as_int(act);
            const float ai = __int_as_float(__builtin_amdgcn_ds_bpermute(aI, av));
            const float af = __int_as_float(__builtin_amdgcn_ds_bpermute(aF, av));
            const float ag = __int_as_float(__builtin_amdgcn_ds_bpermute(aG, av));
            const float ao = __int_as_float(__builtin_amdgcn_ds_bpermute(aO, av));

            // c,h for unit j (all quads compute identical copies)
            c = fmaf(af, c, ai * ag);
            const float th = fmaf(2.f, __builtin_amdgcn_rcpf(1.f + __expf(-2.f * c)), -1.f);
            const float h  = ao * th;

            // h -> wave-uniform regs (VALU readlane, no LDS latency)
            const int hI = __float_as_int(h);
#pragma unroll
            for (int k = 0; k < HID; ++k)
                hs[k] = __int_as_float(__builtin_amdgcn_readlane(hI, k));
        }

        // land next chunk into LDS (loads have had 16 steps to complete)
        if (ci < T_STEPS / CHUNK - 1) {
            float* wp = (float*)xs + (cur ^ 1) * (CHUNK * NG) + lane * 4;
            *(float4*)(wp +   0) = nx0;
            *(float4*)(wp + 256) = nx1;
            *(float4*)(wp + 512) = nx2;
            *(float4*)(wp + 768) = nx3;
        }
    }

    // ---- fused MLP head: lane handles z row 'lane' directly
    float z = b1[lane];
#pragma unroll
    for (int k = 0; k < HID; ++k)
        z = fmaf(W1[lane * HID + k], hs[k], z);
    z = fmaxf(z, 0.f);
    float y = z * W2[lane];

    // wave-wide sum
#pragma unroll
    for (int m = 1; m < 64; m <<= 1) y += __shfl_xor(y, m, 64);

    if (lane == 0)
        out[batch] = 4.f * __builtin_amdgcn_rcpf(1.f + __expf(-(y + b2[0])));
}

extern "C" void kernel_launch(void* const* d_in, const int* in_sizes, int n_in,
                              void* d_out, int out_size, void* d_ws, size_t ws_size,
                              hipStream_t stream) {
    const float* x    = (const float*)d_in[0];
    const float* W_ih = (const float*)d_in[1];
    const float* W_hh = (const float*)d_in[2];
    const float* b_ih = (const float*)d_in[3];
    const float* b_hh = (const float*)d_in[4];
    const float* W1   = (const float*)d_in[5];
    const float* b1   = (const float*)d_in[6];
    const float* W2   = (const float*)d_in[7];
    const float* b2   = (const float*)d_in[8];
    float* out = (float*)d_out;
    float* xg  = (float*)d_ws;   // [B][T][64] = 64 MiB

    xg_gemm<<<dim3(T_STEPS * BATCH / 64), dim3(256), 0, stream>>>(x, W_ih, b_ih, b_hh, xg);
    lstm_scan<<<dim3(BATCH), dim3(64), 0, stream>>>(xg, W_hh, W1, b1, W2, b2, out);
}